// Round 2
// baseline (75.544 us; speedup 1.0000x reference)
//
#include <hip/hip_runtime.h>

// Problem constants
#define B_    8
#define C_    512
#define T_    512
#define O_    512
#define K_    65
#define PAD_  32

// Tiling
#define O_TILE 32                       // o per block
#define T_TILE 128                      // t per block
#define J_     8                        // o per wave
#define NW     4                        // waves per block (256 threads)
#define ROWS   (O_TILE + 2 * PAD_)      // 96 x-tile rows
#define NR     (J_ + 2 * PAD_)          // 72 sliding steps per wave
#define YPITCH 36                       // y-tile pitch (16B-aligned rows)

#define XTILE_ELEMS (ROWS * T_TILE)     // 12288 floats (48 KB)
#define WT_TILE     (NW * NR * J_)      // 2304 floats (9 KB)

__global__ __launch_bounds__(256, 2)
void conv_fused(const float* __restrict__ x,
                const float* __restrict__ w,
                const float* __restrict__ bias,
                float* __restrict__ out) {
    // [x-tile 48 KB][Wt 9 KB]; y-tile (18 KB) later aliases the x-tile region
    __shared__ float smem[XTILE_ELEMS + WT_TILE];
    float* xs  = smem;
    float* wts = smem + XTILE_ELEMS;

    const int tid = threadIdx.x;
    const int bid = blockIdx.x;          // 512 blocks: b(8) x ob(16) x tb(4)
    const int b   = bid >> 6;
    const int rem = bid & 63;
    const int ob  = rem >> 2;            // [0,16)
    const int tb  = rem & 3;             // [0,4)
    const int t0  = tb * T_TILE;
    const int c_base = ob * O_TILE - PAD_;

    // ---- Stage x tile: rows c_base..c_base+95, cols t0..t0+127, zero-padded ----
    {
        const float* xb = x + (size_t)b * (C_ * T_);
        const int l32 = tid & 31;        // 32 lanes * float4 = 128 floats/row
        const int rg  = tid >> 5;        // 8 rows per pass
        #pragma unroll
        for (int rr = 0; rr < ROWS / 8; ++rr) {   // 12 passes
            const int row = rr * 8 + rg;
            const int c   = c_base + row;
            float4 v = make_float4(0.f, 0.f, 0.f, 0.f);
            if (c >= 0 && c < C_)
                v = *(const float4*)(xb + c * T_ + t0 + l32 * 4);
            *(float4*)(&xs[row * T_TILE + l32 * 4]) = v;
        }
    }

    // ---- Stage banded weights: Wt[wg][r][j] = W[(ob*4+wg)*8+j][r-j] ----
    {
        #pragma unroll
        for (int p = 0; p < WT_TILE / 256; ++p) {  // 9 passes
            const int e  = p * 256 + tid;
            const int wg = e / (NR * J_);
            const int r2 = e % (NR * J_);
            const int r  = r2 >> 3;
            const int j  = r2 & 7;
            const int o  = (ob * NW + wg) * J_ + j;
            const int k  = r - j;
            float v = 0.f;
            if (k >= 0 && k < K_) v = w[o * K_ + k];
            wts[e] = v;
        }
    }
    __syncthreads();

    // ---- Compute: wave wu owns o = obase..obase+7, lanes span t (2 each) ----
    const int lane  = tid & 63;
    const int wu    = __builtin_amdgcn_readfirstlane(tid >> 6);
    const int obase = (ob * NW + wu) * J_;

    float2 acc[J_];
    #pragma unroll
    for (int j = 0; j < J_; ++j) {
        const float bj = bias[obase + j];     // uniform -> scalar load
        acc[j] = make_float2(bj, bj);
    }

    const int tl = lane * 2;
    const float* xrow = xs + (wu * J_) * T_TILE + tl;
    const float* wrow = wts + wu * (NR * J_);

    #pragma unroll 4
    for (int r = 0; r < NR; ++r) {            // 72 sliding steps
        const float2 xv = *(const float2*)(xrow + r * T_TILE);
        const float4 wa = *(const float4*)(wrow + r * J_);      // uniform broadcast
        const float4 wb = *(const float4*)(wrow + r * J_ + 4);  // uniform broadcast
        acc[0].x += wa.x * xv.x;  acc[0].y += wa.x * xv.y;
        acc[1].x += wa.y * xv.x;  acc[1].y += wa.y * xv.y;
        acc[2].x += wa.z * xv.x;  acc[2].y += wa.z * xv.y;
        acc[3].x += wa.w * xv.x;  acc[3].y += wa.w * xv.y;
        acc[4].x += wb.x * xv.x;  acc[4].y += wb.x * xv.y;
        acc[5].x += wb.y * xv.x;  acc[5].y += wb.y * xv.y;
        acc[6].x += wb.z * xv.x;  acc[6].y += wb.z * xv.y;
        acc[7].x += wb.w * xv.x;  acc[7].y += wb.w * xv.y;
    }

    __syncthreads();   // x tile dead; reuse as y tile [t][o], pitch YPITCH

    // ---- Transpose through LDS (float4 rows: o-contiguous per thread) ----
    {
        const int olb = wu * J_;
        *(float4*)(&smem[tl * YPITCH + olb])           = make_float4(acc[0].x, acc[1].x, acc[2].x, acc[3].x);
        *(float4*)(&smem[tl * YPITCH + olb + 4])       = make_float4(acc[4].x, acc[5].x, acc[6].x, acc[7].x);
        *(float4*)(&smem[(tl + 1) * YPITCH + olb])     = make_float4(acc[0].y, acc[1].y, acc[2].y, acc[3].y);
        *(float4*)(&smem[(tl + 1) * YPITCH + olb + 4]) = make_float4(acc[4].y, acc[5].y, acc[6].y, acc[7].y);
    }
    __syncthreads();

    // ---- Coalesced global store: 128 t-rows x 32 o (float4 runs) ----
    {
        float* ob_out = out + (size_t)b * (T_ * O_) + (size_t)t0 * O_ + ob * O_TILE;
        const int ol   = (tid & 7) * 4;       // [0,32) step 4
        const int trow = tid >> 3;            // [0,32)
        #pragma unroll
        for (int p = 0; p < 4; ++p) {
            const int t_local = p * 32 + trow;
            const float4 v = *(const float4*)(&smem[t_local * YPITCH + ol]);
            *(float4*)(ob_out + (size_t)t_local * O_ + ol) = v;
        }
    }
}

extern "C" void kernel_launch(void* const* d_in, const int* in_sizes, int n_in,
                              void* d_out, int out_size, void* d_ws, size_t ws_size,
                              hipStream_t stream) {
    const float* x    = (const float*)d_in[0];
    const float* w    = (const float*)d_in[1];
    const float* bias = (const float*)d_in[2];
    float* out = (float*)d_out;

    const int nblocks = B_ * (O_ / O_TILE) * (T_ / T_TILE);   // 512
    conv_fused<<<nblocks, 256, 0, stream>>>(x, w, bias, out);
}

// Round 3
// 74.534 us; speedup vs baseline: 1.0136x; 1.0136x over previous
//
#include <hip/hip_runtime.h>

// Problem constants
#define B_    8
#define C_    512
#define T_    512
#define O_    512
#define K_    65
#define PAD_  32

// Tiling
#define O_TILE 32
#define T_TILE 128
#define J_     8
#define NW     4
#define ROWS   (O_TILE + 2 * PAD_)   // 96
#define NR     (J_ + 2 * PAD_)       // 72
#define YPITCH 36

#define XTILE_ELEMS (ROWS * T_TILE)  // 12288 floats (48 KB)
#define WT_TILE     (NW * NR * J_)   // 2304 floats (9 KB) -- fallback path only
#define NOG        (O_ / J_)         // 64
#define WT_ELEMS   (NOG * NR * J_)   // 36864 floats (144 KB)

// ---- prep: Wt[og][r][j] = W[og*8+j][r-j] (0 outside band) ----
__global__ __launch_bounds__(256) void wt_prep(const float* __restrict__ w,
                                               float* __restrict__ wt) {
    int e = blockIdx.x * 256 + threadIdx.x;
    if (e >= WT_ELEMS) return;
    int og  = e / (NR * J_);
    int rem = e % (NR * J_);
    int r   = rem >> 3;
    int j   = rem & 7;
    int k   = r - j;
    float v = 0.0f;
    if (k >= 0 && k < K_) v = w[(og * J_ + j) * K_ + k];
    wt[e] = v;
}

// USE_WS=true: weights via uniform scalar/L1 loads from d_ws (no LDS pipe cost)
// USE_WS=false: round-2 fallback, weights staged+broadcast from LDS
template <bool USE_WS>
__global__ __launch_bounds__(256, 2)
void conv_main(const float* __restrict__ x,
               const float* __restrict__ w,      // raw weights (fallback)
               const float* __restrict__ wt,     // banded table in ws
               const float* __restrict__ bias,
               float* __restrict__ out) {
    __shared__ float smem[XTILE_ELEMS + (USE_WS ? 0 : WT_TILE)];
    float* xs = smem;

    const int tid = threadIdx.x;
    const int bid = blockIdx.x;          // 512: b(8) x ob(16) x tb(4)
    const int b   = bid >> 6;
    const int rem = bid & 63;
    const int ob  = rem >> 2;
    const int tb  = rem & 3;
    const int t0  = tb * T_TILE;
    const int c_base = ob * O_TILE - PAD_;

    // ---- Stage x tile (96 rows x 128 cols, zero-padded) ----
    {
        const float* xb = x + (size_t)b * (C_ * T_);
        const int l32 = tid & 31;
        const int rg  = tid >> 5;
        #pragma unroll
        for (int rr = 0; rr < ROWS / 8; ++rr) {
            const int row = rr * 8 + rg;
            const int c   = c_base + row;
            float4 v = make_float4(0.f, 0.f, 0.f, 0.f);
            if (c >= 0 && c < C_)
                v = *(const float4*)(xb + c * T_ + t0 + l32 * 4);
            *(float4*)(&xs[row * T_TILE + l32 * 4]) = v;
        }
    }

    // ---- Fallback only: stage banded weights into LDS ----
    if (!USE_WS) {
        float* wts = smem + XTILE_ELEMS;
        #pragma unroll
        for (int p = 0; p < WT_TILE / 256; ++p) {
            const int e  = p * 256 + tid;
            const int wg = e / (NR * J_);
            const int r2 = e % (NR * J_);
            const int r  = r2 >> 3;
            const int j  = r2 & 7;
            const int o  = (ob * NW + wg) * J_ + j;
            const int k  = r - j;
            float v = 0.f;
            if (k >= 0 && k < K_) v = w[o * K_ + k];
            wts[e] = v;
        }
    }
    __syncthreads();

    // ---- Compute ----
    const int lane  = tid & 63;
    const int wu    = __builtin_amdgcn_readfirstlane(tid >> 6);  // uniform
    const int og    = ob * NW + wu;
    const int obase = og * J_;

    float2 acc[J_];
    #pragma unroll
    for (int j = 0; j < J_; ++j) {
        const float bj = bias[obase + j];   // uniform -> scalar load
        acc[j] = make_float2(bj, bj);
    }

    const int tl = lane * 2;
    const float* xrow = xs + (wu * J_) * T_TILE + tl;
    // Uniform weight row pointer: base uniform (og from readfirstlane),
    // index uniform (loop counter) -> scalar loads, zero LDS-pipe cost.
    const float4* wrow = USE_WS
        ? (const float4*)(wt + (size_t)og * (NR * J_))
        : (const float4*)(smem + XTILE_ELEMS + wu * (NR * J_));

    #pragma unroll 8
    for (int r = 0; r < NR; ++r) {
        const float2 xv = *(const float2*)(xrow + r * T_TILE);
        const float4 wa = wrow[2 * r];
        const float4 wb = wrow[2 * r + 1];
        acc[0].x += wa.x * xv.x;  acc[0].y += wa.x * xv.y;
        acc[1].x += wa.y * xv.x;  acc[1].y += wa.y * xv.y;
        acc[2].x += wa.z * xv.x;  acc[2].y += wa.z * xv.y;
        acc[3].x += wa.w * xv.x;  acc[3].y += wa.w * xv.y;
        acc[4].x += wb.x * xv.x;  acc[4].y += wb.x * xv.y;
        acc[5].x += wb.y * xv.x;  acc[5].y += wb.y * xv.y;
        acc[6].x += wb.z * xv.x;  acc[6].y += wb.z * xv.y;
        acc[7].x += wb.w * xv.x;  acc[7].y += wb.w * xv.y;
    }

    __syncthreads();   // x tile dead; reuse as y tile [t][o], pitch YPITCH

    // ---- Transpose through LDS ----
    {
        const int olb = wu * J_;
        *(float4*)(&smem[tl * YPITCH + olb])           = make_float4(acc[0].x, acc[1].x, acc[2].x, acc[3].x);
        *(float4*)(&smem[tl * YPITCH + olb + 4])       = make_float4(acc[4].x, acc[5].x, acc[6].x, acc[7].x);
        *(float4*)(&smem[(tl + 1) * YPITCH + olb])     = make_float4(acc[0].y, acc[1].y, acc[2].y, acc[3].y);
        *(float4*)(&smem[(tl + 1) * YPITCH + olb + 4]) = make_float4(acc[4].y, acc[5].y, acc[6].y, acc[7].y);
    }
    __syncthreads();

    // ---- Coalesced global store ----
    {
        float* ob_out = out + (size_t)b * (T_ * O_) + (size_t)t0 * O_ + ob * O_TILE;
        const int ol   = (tid & 7) * 4;
        const int trow = tid >> 3;
        #pragma unroll
        for (int p = 0; p < 4; ++p) {
            const int t_local = p * 32 + trow;
            const float4 v = *(const float4*)(&smem[t_local * YPITCH + ol]);
            *(float4*)(ob_out + (size_t)t_local * O_ + ol) = v;
        }
    }
}

extern "C" void kernel_launch(void* const* d_in, const int* in_sizes, int n_in,
                              void* d_out, int out_size, void* d_ws, size_t ws_size,
                              hipStream_t stream) {
    const float* x    = (const float*)d_in[0];
    const float* w    = (const float*)d_in[1];
    const float* bias = (const float*)d_in[2];
    float* out = (float*)d_out;
    float* wt  = (float*)d_ws;

    const int nblocks = B_ * (O_ / O_TILE) * (T_ / T_TILE);   // 512

    if (ws_size >= (size_t)WT_ELEMS * sizeof(float)) {
        wt_prep<<<(WT_ELEMS + 255) / 256, 256, 0, stream>>>(w, wt);
        conv_main<true><<<nblocks, 256, 0, stream>>>(x, w, wt, bias, out);
    } else {
        conv_main<false><<<nblocks, 256, 0, stream>>>(x, w, w, bias, out);
    }
}